// Round 6
// baseline (347.427 us; speedup 1.0000x reference)
//
#include <hip/hip_runtime.h>

typedef unsigned short u16;
typedef __attribute__((ext_vector_type(8))) __bf16 bf16x8;
typedef __attribute__((ext_vector_type(4))) float f32x4;

#define DEV __device__ __forceinline__

DEV u16 f2bf(float f) {  // RTNE float->bf16
  unsigned u = __float_as_uint(f);
  u += 0x7fffu + ((u >> 16) & 1u);
  return (u16)(u >> 16);
}
DEV float bf2f(u16 u) { return __uint_as_float((unsigned)u << 16); }

// async global->LDS, 16B per lane. LDS dest is wave-uniform base + lane*16.
DEV void gl_lds16(const void* g, void* l) {
  __builtin_amdgcn_global_load_lds(
      (const __attribute__((address_space(1))) void*)(uintptr_t)g,
      (__attribute__((address_space(3))) void*)(unsigned)(uintptr_t)l, 16, 0, 0);
}

DEV float wave_sum64(float v) {
#pragma unroll
  for (int off = 32; off > 0; off >>= 1) v += __shfl_down(v, off);
  return v;  // lane 0 holds sum
}

// ---------------- LN body (shared by prep & proj_reduce_ln) ----------------
DEV void ln_body(const float4 v, const float* g, const float* be, u16* out_row, int t,
                 float* red) {
  const int w = t >> 6, L = t & 63;
  float s = v.x + v.y + v.z + v.w;
  s = wave_sum64(s);
  if (L == 0) red[w] = s;
  __syncthreads();
  const float mean = (red[0] + red[1] + red[2] + red[3]) * (1.0f / 1024.0f);
  const float dx = v.x - mean, dy = v.y - mean, dz = v.z - mean, dw = v.w - mean;
  float q = dx * dx + dy * dy + dz * dz + dw * dw;
  q = wave_sum64(q);
  if (L == 0) red[4 + w] = q;
  __syncthreads();
  const float var = (red[4] + red[5] + red[6] + red[7]) * (1.0f / 1024.0f);
  const float rs = rsqrtf(var + 1e-5f);
  const float4 gg = reinterpret_cast<const float4*>(g)[t];
  const float4 bb = reinterpret_cast<const float4*>(be)[t];
  ushort4 o;
  o.x = f2bf(dx * rs * gg.x + bb.x);
  o.y = f2bf(dy * rs * gg.y + bb.y);
  o.z = f2bf(dz * rs * gg.z + bb.z);
  o.w = f2bf(dw * rs * gg.w + bb.w);
  reinterpret_cast<ushort4*>(out_row)[t] = o;
}

// ---- prep: ln1(x)->hbuf  +  4 weight transpose-converts, one launch ----
__global__ __launch_bounds__(256) void prep_kernel(
    const float* __restrict__ x, const float* __restrict__ ln1g,
    const float* __restrict__ ln1b, u16* __restrict__ hbuf,
    const float* __restrict__ Wqkv, u16* __restrict__ wt_qkv,
    const float* __restrict__ Wproj, u16* __restrict__ wt_proj,
    const float* __restrict__ Wfc, u16* __restrict__ wt_fc,
    const float* __restrict__ Wout, u16* __restrict__ wt_out) {
  __shared__ float smem[32 * 33];
  int id = blockIdx.x;
  const int t = threadIdx.x;
  if (id < 4096) {
    const float4 v = reinterpret_cast<const float4*>(x + (size_t)id * 1024)[t];
    ln_body(v, ln1g, ln1b, hbuf + (size_t)id * 1024, t, smem);
    return;
  }
  id -= 4096;
  const float* W;
  u16* Wt;
  int K, N, nbx;
  if (id < 3072) {
    W = Wqkv; Wt = wt_qkv; K = 1024; N = 3072; nbx = 96;
  } else if (id < 3072 + 1024) {
    id -= 3072; W = Wproj; Wt = wt_proj; K = 1024; N = 1024; nbx = 32;
  } else if (id < 3072 + 1024 + 4096) {
    id -= 3072 + 1024; W = Wfc; Wt = wt_fc; K = 1024; N = 4096; nbx = 128;
  } else {
    id -= 3072 + 1024 + 4096; W = Wout; Wt = wt_out; K = 4096; N = 1024; nbx = 32;
  }
  float(*tile)[33] = (float(*)[33])smem;
  const int c0 = (id % nbx) * 32, r0 = (id / nbx) * 32;
  const int tx = t & 31, ty = t >> 5;  // ty 0..7
#pragma unroll
  for (int j = 0; j < 4; ++j)
    tile[ty + j * 8][tx] = W[(size_t)(r0 + ty + j * 8) * N + c0 + tx];
  __syncthreads();
#pragma unroll
  for (int j = 0; j < 4; ++j) {
    const int n = c0 + ty + j * 8, k = r0 + tx;
    Wt[(size_t)n * K + k] = f2bf(tile[tx][ty + j * 8]);
  }
}

// ------- fused: x2 = x + bproj + P0 + P1 (fp32 partials); hbuf = LN(x2) bf16 -------
__global__ __launch_bounds__(256) void proj_reduce_ln(const float* __restrict__ x,
                                                      const float* __restrict__ bias,
                                                      const float* __restrict__ P,  // 2 slices
                                                      const float* __restrict__ g,
                                                      const float* __restrict__ be,
                                                      float* __restrict__ x2,
                                                      u16* __restrict__ hbuf) {
  constexpr size_t MN = (size_t)4096 * 1024;
  const int row = blockIdx.x, t = threadIdx.x;
  __shared__ float red[8];
  const float4 xv = reinterpret_cast<const float4*>(x + (size_t)row * 1024)[t];
  const float4 bv = reinterpret_cast<const float4*>(bias)[t];
  const float4 p0 = reinterpret_cast<const float4*>(P + (size_t)row * 1024)[t];
  const float4 p1 = reinterpret_cast<const float4*>(P + MN + (size_t)row * 1024)[t];
  float4 v;
  v.x = xv.x + bv.x + p0.x + p1.x;
  v.y = xv.y + bv.y + p0.y + p1.y;
  v.z = xv.z + bv.z + p0.z + p1.z;
  v.w = xv.w + bv.w + p0.w + p1.w;
  reinterpret_cast<float4*>(x2 + (size_t)row * 1024)[t] = v;
  ln_body(v, g, be, hbuf + (size_t)row * 1024, t, red);
}

// ------- fused: d_out = x2 + bout + P0+P1+P2+P3 (bf16 partials) -------
__global__ __launch_bounds__(256) void out_reduce(const float* __restrict__ x2,
                                                  const float* __restrict__ bias,
                                                  const u16* __restrict__ P0,
                                                  const u16* __restrict__ P1,
                                                  const u16* __restrict__ P2,
                                                  const u16* __restrict__ P3,
                                                  float* __restrict__ dout) {
  const int row = blockIdx.x, t = threadIdx.x;
  const size_t off = (size_t)row * 1024;
  const float4 xv = reinterpret_cast<const float4*>(x2 + off)[t];
  const float4 bv = reinterpret_cast<const float4*>(bias)[t];
  const ushort4 a = reinterpret_cast<const ushort4*>(P0 + off)[t];
  const ushort4 b = reinterpret_cast<const ushort4*>(P1 + off)[t];
  const ushort4 c = reinterpret_cast<const ushort4*>(P2 + off)[t];
  const ushort4 d = reinterpret_cast<const ushort4*>(P3 + off)[t];
  float4 o;
  o.x = xv.x + bv.x + bf2f(a.x) + bf2f(b.x) + bf2f(c.x) + bf2f(d.x);
  o.y = xv.y + bv.y + bf2f(a.y) + bf2f(b.y) + bf2f(c.y) + bf2f(d.y);
  o.z = xv.z + bv.z + bf2f(a.z) + bf2f(b.z) + bf2f(c.z) + bf2f(d.z);
  o.w = xv.w + bv.w + bf2f(a.w) + bf2f(b.w) + bf2f(c.w) + bf2f(d.w);
  reinterpret_cast<float4*>(dout + off)[t] = o;
}

// ------------- V slice of qkv [b,s,2048+h*64+d] -> Vt [b,h,d,s] -------------
__global__ __launch_bounds__(256) void transpose_v(const u16* __restrict__ qkv,
                                                   u16* __restrict__ Vt) {
  __shared__ __attribute__((aligned(16))) u16 tile[64][72];
  const int s0 = blockIdx.x * 64;
  const int h = blockIdx.y, b = blockIdx.z;
  const int t = threadIdx.x;
#pragma unroll
  for (int i = 0; i < 2; ++i) {
    const int idx = i * 256 + t, r = idx >> 3, c = (idx & 7) << 3;
    const uint4 v =
        *(const uint4*)(qkv + (size_t)(b * 2048 + s0 + r) * 3072 + 2048 + h * 64 + c);
    *(uint4*)&tile[r][c] = v;
  }
  __syncthreads();
#pragma unroll
  for (int i = 0; i < 2; ++i) {
    const int idx = i * 256 + t, d = idx >> 3, sc = (idx & 7) << 3;
    u16 tmp[8];
#pragma unroll
    for (int j = 0; j < 8; ++j) tmp[j] = tile[sc + j][d];
    *(uint4*)(Vt + (size_t)((b * 16 + h) * 64 + d) * 2048 + s0 + sc) = *(uint4*)tmp;
  }
}

// ---------------- GEMM: C[M,N] = A[M,K](bf16) @ Bt[N,K]^T(bf16) + epilogue --------
// BK=64 (32 MFMA per barrier drain).  1-D grid, XCD-banded swizzle: xcd = id&7 owns
// n-tiles [xcd*band, (xcd+1)*band) for all m -> per-XCD B working set <=1 MB stays
// L2-resident.  blockIdx.z = K-slice (split-K).
enum { F_BIAS = 1, F_RESID = 2, F_RELU = 4, F_BF16 = 8, F_SLICED = 16, F_PART4 = 32 };

template <int FLAGS>
__global__ __launch_bounds__(256, 2) void gemm_bt(const u16* __restrict__ A,
                                                  const u16* __restrict__ Bt,
                                                  const float* __restrict__ bias,
                                                  const float* __restrict__ resid,
                                                  void* __restrict__ Cout,
                                                  u16* __restrict__ pp0, u16* __restrict__ pp1,
                                                  u16* __restrict__ pp2, u16* __restrict__ pp3,
                                                  int M, int N, int K, int Kst, int nbx) {
  __shared__ __attribute__((aligned(16))) u16 sA[2][128 * 32];
  __shared__ __attribute__((aligned(16))) u16 sB[2][128 * 32];
  const int t = threadIdx.x, w = t >> 6, L = t & 63, quad = L >> 4, l15 = L & 15;
  const int wm = w >> 1, wn = w & 1;
  // XCD-banded decode (dispatch round-robins id%8 across XCDs)
  const int id = blockIdx.x;
  const int band = nbx >> 3;
  const int xcd = id & 7, slot = id >> 3;
  const int n0 = (xcd * band + slot % band) * 128;
  const int m0 = (slot / band) * 128;
  const u16* Ag = A + (size_t)m0 * Kst + (size_t)blockIdx.z * K;
  const u16* Bg = Bt + (size_t)n0 * Kst + (size_t)blockIdx.z * K;

  f32x4 acc[4][4] = {};

  for (int k0 = 0; k0 < K; k0 += 64) {
    __syncthreads();
#pragma unroll
    for (int h = 0; h < 2; ++h) {
#pragma unroll
      for (int i = 0; i < 2; ++i) {
        const int cp = i * 256 + t, rr = cp >> 2, cc = (cp & 3) << 3;
        gl_lds16(Ag + (size_t)rr * Kst + k0 + h * 32 + cc, &sA[h][(i * 256 + w * 64) * 8]);
      }
#pragma unroll
      for (int i = 0; i < 2; ++i) {
        const int cp = i * 256 + t, rr = cp >> 2, cc = (cp & 3) << 3;
        gl_lds16(Bg + (size_t)rr * Kst + k0 + h * 32 + cc, &sB[h][(i * 256 + w * 64) * 8]);
      }
    }
    __syncthreads();

#pragma unroll
    for (int h = 0; h < 2; ++h) {
      bf16x8 af[4], bfr[4];
#pragma unroll
      for (int m = 0; m < 4; ++m)
        af[m] = *(const bf16x8*)&sA[h][(wm * 64 + m * 16 + l15) * 32 + quad * 8];
#pragma unroll
      for (int n = 0; n < 4; ++n)
        bfr[n] = *(const bf16x8*)&sB[h][(wn * 64 + n * 16 + l15) * 32 + quad * 8];
#pragma unroll
      for (int m = 0; m < 4; ++m)
#pragma unroll
        for (int n = 0; n < 4; ++n)
          acc[m][n] =
              __builtin_amdgcn_mfma_f32_16x16x32_bf16(af[m], bfr[n], acc[m][n], 0, 0, 0);
    }
  }

  u16* pbase = nullptr;
  if (FLAGS & F_PART4)
    pbase = (blockIdx.z == 0) ? pp0 : (blockIdx.z == 1) ? pp1 : (blockIdx.z == 2) ? pp2 : pp3;
  float* sbase = nullptr;
  if (FLAGS & F_SLICED) sbase = (float*)Cout + (size_t)blockIdx.z * M * N;

#pragma unroll
  for (int m = 0; m < 4; ++m) {
#pragma unroll
    for (int n = 0; n < 4; ++n) {
      const int col = n0 + wn * 64 + n * 16 + l15;
      const float bv = (FLAGS & F_BIAS) ? bias[col] : 0.0f;
#pragma unroll
      for (int rr = 0; rr < 4; ++rr) {
        const int row = m0 + wm * 64 + m * 16 + quad * 4 + rr;
        if (FLAGS & F_PART4) {
          pbase[(size_t)row * N + col] = f2bf(acc[m][n][rr]);
        } else if (FLAGS & F_SLICED) {
          sbase[(size_t)row * N + col] = acc[m][n][rr];
        } else {
          float v = acc[m][n][rr] + bv;
          if (FLAGS & F_RESID) v += resid[(size_t)row * N + col];
          if (FLAGS & F_RELU) v = fmaxf(v, 0.0f);
          if (FLAGS & F_BF16)
            ((u16*)Cout)[(size_t)row * N + col] = f2bf(v);
          else
            ((float*)Cout)[(size_t)row * N + col] = v;
        }
      }
    }
  }
}

// ---------------- Flash attention (causal), bf16 MFMA, no-max softmax ----------------
__global__ __launch_bounds__(256) void flash_attn(const u16* __restrict__ qkv,
                                                  const u16* __restrict__ Vt,
                                                  u16* __restrict__ y) {
  constexpr int S = 2048, D3 = 3072, D = 1024;
  constexpr float Csc = 0.125f * 1.44269504088896f;  // scale * log2(e)
  __shared__ __attribute__((aligned(16))) u16 sK[2 * 64 * 32];    // [kk][kv][k%32]
  __shared__ __attribute__((aligned(16))) u16 sV[2 * 64 * 32];    // [kk over kv][d][kv%32]
  __shared__ __attribute__((aligned(16))) u16 sP[4][2 * 16 * 40]; // per-wave, pad stride 40

  const int lin = blockIdx.x;  // 0..1023
  const int half = lin >> 9, rem = lin & 511;
  const int qt = half ? (31 - (rem & 31)) : (rem & 31);
  const int bh = (rem >> 5) | (half << 4);  // 0..31
  const int b = bh >> 4, h = bh & 15;
  const int q0 = qt * 64;

  const int t = threadIdx.x, w = t >> 6, L = t & 63, quad = L >> 4, l15 = L & 15;
  const int qw = q0 + w * 16;  // this wave's first q row

  const u16* qbase = qkv + (size_t)(b * S) * D3 + h * 64;
  const u16* Kbase = qbase + D;
  const u16* Vbase = Vt + (size_t)((b * 16 + h) * 64) * S;

  bf16x8 aQ[2];
#pragma unroll
  for (int kk = 0; kk < 2; ++kk)
    aQ[kk] = *(const bf16x8*)(qbase + (size_t)(qw + l15) * D3 + kk * 32 + quad * 8);

  bf16x8 ones;
#pragma unroll
  for (int i = 0; i < 8; ++i) ones[i] = (__bf16)1.0f;

  f32x4 acc[4] = {};
  f32x4 lacc = {};

  u16* sPw = sP[w];
  const int nkv = qt + 1;
  for (int it = 0; it < nkv; ++it) {
    const int kv0 = it * 64;
    __syncthreads();
#pragma unroll
    for (int i = 0; i < 2; ++i) {
      const int cp = i * 256 + t;
      const int kk = cp >> 8, r = (cp >> 2) & 63, col = (cp & 3) << 3;
      gl_lds16(Kbase + (size_t)(kv0 + r) * D3 + kk * 32 + col, &sK[(i * 256 + w * 64) * 8]);
    }
#pragma unroll
    for (int i = 0; i < 2; ++i) {
      const int cp = i * 256 + t;
      const int kk = cp >> 8, d = (cp >> 2) & 63, col = (cp & 3) << 3;
      gl_lds16(Vbase + (size_t)d * S + kv0 + kk * 32 + col, &sV[(i * 256 + w * 64) * 8]);
    }
    __syncthreads();

    f32x4 s[4] = {};
#pragma unroll
    for (int kk = 0; kk < 2; ++kk) {
#pragma unroll
      for (int n = 0; n < 4; ++n) {
        const bf16x8 bK = *(const bf16x8*)&sK[kk * 2048 + (n * 16 + l15) * 32 + quad * 8];
        s[n] = __builtin_amdgcn_mfma_f32_16x16x32_bf16(aQ[kk], bK, s[n], 0, 0, 0);
      }
    }

    if (kv0 + 63 > qw) {
#pragma unroll
      for (int n = 0; n < 4; ++n) {
        const int col = kv0 + n * 16 + l15;
#pragma unroll
        for (int r = 0; r < 4; ++r) {
          const int row = qw + quad * 4 + r;
          const float p = __builtin_amdgcn_exp2f(s[n][r] * Csc);
          s[n][r] = (col > row) ? 0.0f : p;
        }
      }
    } else {
#pragma unroll
      for (int n = 0; n < 4; ++n)
#pragma unroll
        for (int r = 0; r < 4; ++r) s[n][r] = __builtin_amdgcn_exp2f(s[n][r] * Csc);
    }

#pragma unroll
    for (int n = 0; n < 4; ++n)
#pragma unroll
      for (int r = 0; r < 4; ++r)
        sPw[(n >> 1) * 640 + (quad * 4 + r) * 40 + (n & 1) * 16 + l15] = f2bf(s[n][r]);

#pragma unroll
    for (int kk = 0; kk < 2; ++kk) {
      const bf16x8 aP = *(const bf16x8*)&sPw[kk * 640 + l15 * 40 + quad * 8];
      lacc = __builtin_amdgcn_mfma_f32_16x16x32_bf16(aP, ones, lacc, 0, 0, 0);
#pragma unroll
      for (int dn = 0; dn < 4; ++dn) {
        const bf16x8 bV = *(const bf16x8*)&sV[kk * 2048 + (dn * 16 + l15) * 32 + quad * 8];
        acc[dn] = __builtin_amdgcn_mfma_f32_16x16x32_bf16(aP, bV, acc[dn], 0, 0, 0);
      }
    }
  }

#pragma unroll
  for (int r = 0; r < 4; ++r) {
    const float inv = 1.0f / lacc[r];
    const int row = qw + quad * 4 + r;
    u16* yb = y + (size_t)(b * S + row) * D + h * 64 + l15;
#pragma unroll
    for (int dn = 0; dn < 4; ++dn) yb[dn * 16] = f2bf(acc[dn][r] * inv);
  }
}

// ---------------- host ----------------
extern "C" void kernel_launch(void* const* d_in, const int* in_sizes, int n_in,
                              void* d_out, int out_size, void* d_ws, size_t ws_size,
                              hipStream_t stream) {
  const float* x = (const float*)d_in[0];
  const float* ln1g = (const float*)d_in[1];
  const float* ln1b = (const float*)d_in[2];
  const float* ln2g = (const float*)d_in[3];
  const float* ln2b = (const float*)d_in[4];
  const float* Wqkv = (const float*)d_in[5];
  const float* bqkv = (const float*)d_in[6];
  const float* Wproj = (const float*)d_in[7];
  const float* bproj = (const float*)d_in[8];
  const float* Wfc = (const float*)d_in[9];
  const float* bfc = (const float*)d_in[10];
  const float* Wout = (const float*)d_in[11];
  const float* bout = (const float*)d_in[12];

  char* ws = (char*)d_ws;
  const size_t MB = 1u << 20;
  // Liveness-based layout; peak 88 MB.
  u16* wt_out = (u16*)(ws + 0 * MB);    //  0- 8  [until out gemm]
  u16* hbuf = (u16*)(ws + 8 * MB);      //  8-16  [ln1->qkv; ln2->fc]
  float* x2 = (float*)(ws + 16 * MB);   // 16-32  [proj_reduce -> out_reduce]
  u16* ybuf = (u16*)(ws + 32 * MB);     // 32-40  [flash -> proj gemm]
  u16* qkvb = (u16*)(ws + 40 * MB);     // 40-64  [qkv gemm -> flash]
  u16* vtb = (u16*)(ws + 64 * MB);      // 64-72  [transpose_v -> flash]
  u16* wt_qkv = (u16*)(ws + 72 * MB);   // 72-78  [until qkv gemm]
  u16* wt_proj = (u16*)(ws + 78 * MB);  // 78-80  [until proj gemm]
  u16* wt_fc = (u16*)(ws + 80 * MB);    // 80-88  [until fc gemm]
  float* projP = (float*)(ws + 40 * MB);// 40-72  fp32 x2 slices (qkvb/vtb dead)
  u16* m1 = (u16*)(ws + 40 * MB);       // 40-72  fc out bf16 (projP dead)
  u16* po0 = (u16*)(ws + 8 * MB);       // hbuf dead after fc
  u16* po1 = (u16*)(ws + 32 * MB);      // ybuf dead after proj
  u16* po2 = (u16*)(ws + 72 * MB);      // wt_qkv/wt_proj dead
  u16* po3 = (u16*)(ws + 80 * MB);      // wt_fc dead after fc

  // ln1 + all 4 weight transposes in one launch
  prep_kernel<<<4096 + 3072 + 1024 + 4096 + 4096, 256, 0, stream>>>(
      x, ln1g, ln1b, hbuf, Wqkv, wt_qkv, Wproj, wt_proj, Wfc, wt_fc, Wout, wt_out);

  gemm_bt<F_BIAS | F_BF16><<<dim3(768, 1, 1), 256, 0, stream>>>(
      hbuf, wt_qkv, bqkv, nullptr, qkvb, nullptr, nullptr, nullptr, nullptr,
      4096, 3072, 1024, 1024, 24);
  transpose_v<<<dim3(32, 16, 2), 256, 0, stream>>>(qkvb, vtb);
  flash_attn<<<1024, 256, 0, stream>>>(qkvb, vtb, ybuf);

  // proj: split-K=2 into fp32 partials, then fused residual+bias+LN2
  gemm_bt<F_SLICED><<<dim3(256, 1, 2), 256, 0, stream>>>(
      ybuf, wt_proj, nullptr, nullptr, projP, nullptr, nullptr, nullptr, nullptr,
      4096, 1024, 512, 1024, 8);
  proj_reduce_ln<<<4096, 256, 0, stream>>>(x, bproj, projP, ln2g, ln2b, x2, hbuf);

  gemm_bt<F_BIAS | F_RELU | F_BF16><<<dim3(1024, 1, 1), 256, 0, stream>>>(
      hbuf, wt_fc, bfc, nullptr, m1, nullptr, nullptr, nullptr, nullptr,
      4096, 4096, 1024, 1024, 32);

  // out: split-K=4 into bf16 partials, then fused residual+bias reduce
  gemm_bt<F_PART4><<<dim3(256, 1, 4), 256, 0, stream>>>(
      m1, wt_out, nullptr, nullptr, nullptr, po0, po1, po2, po3,
      4096, 1024, 1024, 4096, 8);
  out_reduce<<<4096, 256, 0, stream>>>(x2, bout, po0, po1, po2, po3, (float*)d_out);
}

// Round 7
// 335.063 us; speedup vs baseline: 1.0369x; 1.0369x over previous
//
#include <hip/hip_runtime.h>

typedef unsigned short u16;
typedef __attribute__((ext_vector_type(8))) __bf16 bf16x8;
typedef __attribute__((ext_vector_type(4))) float f32x4;

#define DEV __device__ __forceinline__

DEV u16 f2bf(float f) {  // RTNE float->bf16
  unsigned u = __float_as_uint(f);
  u += 0x7fffu + ((u >> 16) & 1u);
  return (u16)(u >> 16);
}
DEV float bf2f(u16 u) { return __uint_as_float((unsigned)u << 16); }

// async global->LDS, 16B per lane. LDS dest is wave-uniform base + lane*16.
DEV void gl_lds16(const void* g, void* l) {
  __builtin_amdgcn_global_load_lds(
      (const __attribute__((address_space(1))) void*)(uintptr_t)g,
      (__attribute__((address_space(3))) void*)(unsigned)(uintptr_t)l, 16, 0, 0);
}

DEV float wave_sum64(float v) {
#pragma unroll
  for (int off = 32; off > 0; off >>= 1) v += __shfl_down(v, off);
  return v;  // lane 0 holds sum
}

// ---------------- LN body (shared by prep & proj_reduce_ln) ----------------
DEV void ln_body(const float4 v, const float* g, const float* be, u16* out_row, int t,
                 float* red) {
  const int w = t >> 6, L = t & 63;
  float s = v.x + v.y + v.z + v.w;
  s = wave_sum64(s);
  if (L == 0) red[w] = s;
  __syncthreads();
  const float mean = (red[0] + red[1] + red[2] + red[3]) * (1.0f / 1024.0f);
  const float dx = v.x - mean, dy = v.y - mean, dz = v.z - mean, dw = v.w - mean;
  float q = dx * dx + dy * dy + dz * dz + dw * dw;
  q = wave_sum64(q);
  if (L == 0) red[4 + w] = q;
  __syncthreads();
  const float var = (red[4] + red[5] + red[6] + red[7]) * (1.0f / 1024.0f);
  const float rs = rsqrtf(var + 1e-5f);
  const float4 gg = reinterpret_cast<const float4*>(g)[t];
  const float4 bb = reinterpret_cast<const float4*>(be)[t];
  ushort4 o;
  o.x = f2bf(dx * rs * gg.x + bb.x);
  o.y = f2bf(dy * rs * gg.y + bb.y);
  o.z = f2bf(dz * rs * gg.z + bb.z);
  o.w = f2bf(dw * rs * gg.w + bb.w);
  reinterpret_cast<ushort4*>(out_row)[t] = o;
}

// ---- prep: ln1(x)->hbuf  +  4 weight transpose-converts, one launch ----
__global__ __launch_bounds__(256) void prep_kernel(
    const float* __restrict__ x, const float* __restrict__ ln1g,
    const float* __restrict__ ln1b, u16* __restrict__ hbuf,
    const float* __restrict__ Wqkv, u16* __restrict__ wt_qkv,
    const float* __restrict__ Wproj, u16* __restrict__ wt_proj,
    const float* __restrict__ Wfc, u16* __restrict__ wt_fc,
    const float* __restrict__ Wout, u16* __restrict__ wt_out) {
  __shared__ float smem[32 * 33];
  int id = blockIdx.x;
  const int t = threadIdx.x;
  if (id < 4096) {
    const float4 v = reinterpret_cast<const float4*>(x + (size_t)id * 1024)[t];
    ln_body(v, ln1g, ln1b, hbuf + (size_t)id * 1024, t, smem);
    return;
  }
  id -= 4096;
  const float* W;
  u16* Wt;
  int K, N, nbx;
  if (id < 3072) {
    W = Wqkv; Wt = wt_qkv; K = 1024; N = 3072; nbx = 96;
  } else if (id < 3072 + 1024) {
    id -= 3072; W = Wproj; Wt = wt_proj; K = 1024; N = 1024; nbx = 32;
  } else if (id < 3072 + 1024 + 4096) {
    id -= 3072 + 1024; W = Wfc; Wt = wt_fc; K = 1024; N = 4096; nbx = 128;
  } else {
    id -= 3072 + 1024 + 4096; W = Wout; Wt = wt_out; K = 4096; N = 1024; nbx = 32;
  }
  float(*tile)[33] = (float(*)[33])smem;
  const int c0 = (id % nbx) * 32, r0 = (id / nbx) * 32;
  const int tx = t & 31, ty = t >> 5;  // ty 0..7
#pragma unroll
  for (int j = 0; j < 4; ++j)
    tile[ty + j * 8][tx] = W[(size_t)(r0 + ty + j * 8) * N + c0 + tx];
  __syncthreads();
#pragma unroll
  for (int j = 0; j < 4; ++j) {
    const int n = c0 + ty + j * 8, k = r0 + tx;
    Wt[(size_t)n * K + k] = f2bf(tile[tx][ty + j * 8]);
  }
}

// ------- fused: x2 = x + bproj + P0 + P1 (bf16 partials); hbuf = LN(x2) bf16 -------
__global__ __launch_bounds__(256) void proj_reduce_ln(const float* __restrict__ x,
                                                      const float* __restrict__ bias,
                                                      const u16* __restrict__ P0,
                                                      const u16* __restrict__ P1,
                                                      const float* __restrict__ g,
                                                      const float* __restrict__ be,
                                                      float* __restrict__ x2,
                                                      u16* __restrict__ hbuf) {
  const int row = blockIdx.x, t = threadIdx.x;
  const size_t off = (size_t)row * 1024;
  __shared__ float red[8];
  const float4 xv = reinterpret_cast<const float4*>(x + off)[t];
  const float4 bv = reinterpret_cast<const float4*>(bias)[t];
  const ushort4 p0 = reinterpret_cast<const ushort4*>(P0 + off)[t];
  const ushort4 p1 = reinterpret_cast<const ushort4*>(P1 + off)[t];
  float4 v;
  v.x = xv.x + bv.x + bf2f(p0.x) + bf2f(p1.x);
  v.y = xv.y + bv.y + bf2f(p0.y) + bf2f(p1.y);
  v.z = xv.z + bv.z + bf2f(p0.z) + bf2f(p1.z);
  v.w = xv.w + bv.w + bf2f(p0.w) + bf2f(p1.w);
  reinterpret_cast<float4*>(x2 + off)[t] = v;
  ln_body(v, g, be, hbuf + off, t, red);
}

// ------- fused: d_out = x2 + bout + P0+P1+P2+P3 (bf16 partials) -------
__global__ __launch_bounds__(256) void out_reduce(const float* __restrict__ x2,
                                                  const float* __restrict__ bias,
                                                  const u16* __restrict__ P0,
                                                  const u16* __restrict__ P1,
                                                  const u16* __restrict__ P2,
                                                  const u16* __restrict__ P3,
                                                  float* __restrict__ dout) {
  const int row = blockIdx.x, t = threadIdx.x;
  const size_t off = (size_t)row * 1024;
  const float4 xv = reinterpret_cast<const float4*>(x2 + off)[t];
  const float4 bv = reinterpret_cast<const float4*>(bias)[t];
  const ushort4 a = reinterpret_cast<const ushort4*>(P0 + off)[t];
  const ushort4 b = reinterpret_cast<const ushort4*>(P1 + off)[t];
  const ushort4 c = reinterpret_cast<const ushort4*>(P2 + off)[t];
  const ushort4 d = reinterpret_cast<const ushort4*>(P3 + off)[t];
  float4 o;
  o.x = xv.x + bv.x + bf2f(a.x) + bf2f(b.x) + bf2f(c.x) + bf2f(d.x);
  o.y = xv.y + bv.y + bf2f(a.y) + bf2f(b.y) + bf2f(c.y) + bf2f(d.y);
  o.z = xv.z + bv.z + bf2f(a.z) + bf2f(b.z) + bf2f(c.z) + bf2f(d.z);
  o.w = xv.w + bv.w + bf2f(a.w) + bf2f(b.w) + bf2f(c.w) + bf2f(d.w);
  reinterpret_cast<float4*>(dout + off)[t] = o;
}

// ---------------- GEMM: C[M,N] = A[M,K](bf16) @ Bt[N,K]^T(bf16) + epilogue --------
// BK=64 (32 MFMA per barrier drain).  blockIdx.y = m-tile, x = n-tile, z = K-slice.
// F_PART4: bf16 partial at pp[z].  F_VT: blocks with n0>=2048 write C transposed
// into pp0 as V^T [b,h,d,s] (fuses the V-transpose into the qkv epilogue).
enum { F_BIAS = 1, F_RESID = 2, F_RELU = 4, F_BF16 = 8, F_PART4 = 32, F_VT = 64 };

template <int FLAGS>
__global__ __launch_bounds__(256, 2) void gemm_bt(const u16* __restrict__ A,
                                                  const u16* __restrict__ Bt,
                                                  const float* __restrict__ bias,
                                                  const float* __restrict__ resid,
                                                  void* __restrict__ Cout,
                                                  u16* __restrict__ pp0, u16* __restrict__ pp1,
                                                  u16* __restrict__ pp2, u16* __restrict__ pp3,
                                                  int M, int N, int K, int Kst) {
  __shared__ __attribute__((aligned(16))) u16 sA[2][128 * 32];
  __shared__ __attribute__((aligned(16))) u16 sB[2][128 * 32];
  const int t = threadIdx.x, w = t >> 6, L = t & 63, quad = L >> 4, l15 = L & 15;
  const int wm = w >> 1, wn = w & 1;
  const int m0 = blockIdx.y * 128, n0 = blockIdx.x * 128;
  const u16* Ag = A + (size_t)m0 * Kst + (size_t)blockIdx.z * K;
  const u16* Bg = Bt + (size_t)n0 * Kst + (size_t)blockIdx.z * K;

  f32x4 acc[4][4] = {};

  for (int k0 = 0; k0 < K; k0 += 64) {
    __syncthreads();
#pragma unroll
    for (int h = 0; h < 2; ++h) {
#pragma unroll
      for (int i = 0; i < 2; ++i) {
        const int cp = i * 256 + t, rr = cp >> 2, cc = (cp & 3) << 3;
        gl_lds16(Ag + (size_t)rr * Kst + k0 + h * 32 + cc, &sA[h][(i * 256 + w * 64) * 8]);
      }
#pragma unroll
      for (int i = 0; i < 2; ++i) {
        const int cp = i * 256 + t, rr = cp >> 2, cc = (cp & 3) << 3;
        gl_lds16(Bg + (size_t)rr * Kst + k0 + h * 32 + cc, &sB[h][(i * 256 + w * 64) * 8]);
      }
    }
    __syncthreads();

#pragma unroll
    for (int h = 0; h < 2; ++h) {
      bf16x8 af[4], bfr[4];
#pragma unroll
      for (int m = 0; m < 4; ++m)
        af[m] = *(const bf16x8*)&sA[h][(wm * 64 + m * 16 + l15) * 32 + quad * 8];
#pragma unroll
      for (int n = 0; n < 4; ++n)
        bfr[n] = *(const bf16x8*)&sB[h][(wn * 64 + n * 16 + l15) * 32 + quad * 8];
#pragma unroll
      for (int m = 0; m < 4; ++m)
#pragma unroll
        for (int n = 0; n < 4; ++n)
          acc[m][n] =
              __builtin_amdgcn_mfma_f32_16x16x32_bf16(af[m], bfr[n], acc[m][n], 0, 0, 0);
    }
  }

  if ((FLAGS & F_VT) && n0 >= 2048) {
    // V block of the qkv GEMM: write C transposed into pp0 = Vt [b,h,d,s] (bf16)
#pragma unroll
    for (int m = 0; m < 4; ++m) {
#pragma unroll
      for (int n = 0; n < 4; ++n) {
        const int col = n0 + wn * 64 + n * 16 + l15;
        const float bv = bias[col];
        const int hh = (col - 2048) >> 6, dd = col & 63;
        const int srow = m0 + wm * 64 + m * 16 + quad * 4;
        const int bb = srow >> 11, ss = srow & 2047;
        ushort4 tmp;
        tmp.x = f2bf(acc[m][n][0] + bv);
        tmp.y = f2bf(acc[m][n][1] + bv);
        tmp.z = f2bf(acc[m][n][2] + bv);
        tmp.w = f2bf(acc[m][n][3] + bv);
        *(ushort4*)(pp0 + ((size_t)((bb * 16 + hh) * 64 + dd)) * 2048 + ss) = tmp;
      }
    }
    return;
  }

  u16* pbase = nullptr;
  if (FLAGS & F_PART4)
    pbase = (blockIdx.z == 0) ? pp0 : (blockIdx.z == 1) ? pp1 : (blockIdx.z == 2) ? pp2 : pp3;

#pragma unroll
  for (int m = 0; m < 4; ++m) {
#pragma unroll
    for (int n = 0; n < 4; ++n) {
      const int col = n0 + wn * 64 + n * 16 + l15;
      const float bv = (FLAGS & F_BIAS) ? bias[col] : 0.0f;
#pragma unroll
      for (int rr = 0; rr < 4; ++rr) {
        const int row = m0 + wm * 64 + m * 16 + quad * 4 + rr;
        if (FLAGS & F_PART4) {
          pbase[(size_t)row * N + col] = f2bf(acc[m][n][rr]);
        } else {
          float v = acc[m][n][rr] + bv;
          if (FLAGS & F_RESID) v += resid[(size_t)row * N + col];
          if (FLAGS & F_RELU) v = fmaxf(v, 0.0f);
          if (FLAGS & F_BF16)
            ((u16*)Cout)[(size_t)row * N + col] = f2bf(v);
          else
            ((float*)Cout)[(size_t)row * N + col] = v;
        }
      }
    }
  }
}

// ---------------- Flash attention (causal), bf16 MFMA, no-max softmax ----------------
__global__ __launch_bounds__(256) void flash_attn(const u16* __restrict__ qkv,
                                                  const u16* __restrict__ Vt,
                                                  u16* __restrict__ y) {
  constexpr int S = 2048, D3 = 3072, D = 1024;
  constexpr float Csc = 0.125f * 1.44269504088896f;  // scale * log2(e)
  __shared__ __attribute__((aligned(16))) u16 sK[2 * 64 * 32];    // [kk][kv][k%32]
  __shared__ __attribute__((aligned(16))) u16 sV[2 * 64 * 32];    // [kk over kv][d][kv%32]
  __shared__ __attribute__((aligned(16))) u16 sP[4][2 * 16 * 40]; // per-wave, pad stride 40

  const int lin = blockIdx.x;  // 0..1023
  const int half = lin >> 9, rem = lin & 511;
  const int qt = half ? (31 - (rem & 31)) : (rem & 31);
  const int bh = (rem >> 5) | (half << 4);  // 0..31
  const int b = bh >> 4, h = bh & 15;
  const int q0 = qt * 64;

  const int t = threadIdx.x, w = t >> 6, L = t & 63, quad = L >> 4, l15 = L & 15;
  const int qw = q0 + w * 16;  // this wave's first q row

  const u16* qbase = qkv + (size_t)(b * S) * D3 + h * 64;
  const u16* Kbase = qbase + D;
  const u16* Vbase = Vt + (size_t)((b * 16 + h) * 64) * S;

  bf16x8 aQ[2];
#pragma unroll
  for (int kk = 0; kk < 2; ++kk)
    aQ[kk] = *(const bf16x8*)(qbase + (size_t)(qw + l15) * D3 + kk * 32 + quad * 8);

  bf16x8 ones;
#pragma unroll
  for (int i = 0; i < 8; ++i) ones[i] = (__bf16)1.0f;

  f32x4 acc[4] = {};
  f32x4 lacc = {};

  u16* sPw = sP[w];
  const int nkv = qt + 1;
  for (int it = 0; it < nkv; ++it) {
    const int kv0 = it * 64;
    __syncthreads();
#pragma unroll
    for (int i = 0; i < 2; ++i) {
      const int cp = i * 256 + t;
      const int kk = cp >> 8, r = (cp >> 2) & 63, col = (cp & 3) << 3;
      gl_lds16(Kbase + (size_t)(kv0 + r) * D3 + kk * 32 + col, &sK[(i * 256 + w * 64) * 8]);
    }
#pragma unroll
    for (int i = 0; i < 2; ++i) {
      const int cp = i * 256 + t;
      const int kk = cp >> 8, d = (cp >> 2) & 63, col = (cp & 3) << 3;
      gl_lds16(Vbase + (size_t)d * S + kv0 + kk * 32 + col, &sV[(i * 256 + w * 64) * 8]);
    }
    __syncthreads();

    f32x4 s[4] = {};
#pragma unroll
    for (int kk = 0; kk < 2; ++kk) {
#pragma unroll
      for (int n = 0; n < 4; ++n) {
        const bf16x8 bK = *(const bf16x8*)&sK[kk * 2048 + (n * 16 + l15) * 32 + quad * 8];
        s[n] = __builtin_amdgcn_mfma_f32_16x16x32_bf16(aQ[kk], bK, s[n], 0, 0, 0);
      }
    }

    if (kv0 + 63 > qw) {
#pragma unroll
      for (int n = 0; n < 4; ++n) {
        const int col = kv0 + n * 16 + l15;
#pragma unroll
        for (int r = 0; r < 4; ++r) {
          const int row = qw + quad * 4 + r;
          const float p = __builtin_amdgcn_exp2f(s[n][r] * Csc);
          s[n][r] = (col > row) ? 0.0f : p;
        }
      }
    } else {
#pragma unroll
      for (int n = 0; n < 4; ++n)
#pragma unroll
        for (int r = 0; r < 4; ++r) s[n][r] = __builtin_amdgcn_exp2f(s[n][r] * Csc);
    }

#pragma unroll
    for (int n = 0; n < 4; ++n)
#pragma unroll
      for (int r = 0; r < 4; ++r)
        sPw[(n >> 1) * 640 + (quad * 4 + r) * 40 + (n & 1) * 16 + l15] = f2bf(s[n][r]);

#pragma unroll
    for (int kk = 0; kk < 2; ++kk) {
      const bf16x8 aP = *(const bf16x8*)&sPw[kk * 640 + l15 * 40 + quad * 8];
      lacc = __builtin_amdgcn_mfma_f32_16x16x32_bf16(aP, ones, lacc, 0, 0, 0);
#pragma unroll
      for (int dn = 0; dn < 4; ++dn) {
        const bf16x8 bV = *(const bf16x8*)&sV[kk * 2048 + (dn * 16 + l15) * 32 + quad * 8];
        acc[dn] = __builtin_amdgcn_mfma_f32_16x16x32_bf16(aP, bV, acc[dn], 0, 0, 0);
      }
    }
  }

#pragma unroll
  for (int r = 0; r < 4; ++r) {
    const float inv = 1.0f / lacc[r];
    const int row = qw + quad * 4 + r;
    u16* yb = y + (size_t)(b * S + row) * D + h * 64 + l15;
#pragma unroll
    for (int dn = 0; dn < 4; ++dn) yb[dn * 16] = f2bf(acc[dn][r] * inv);
  }
}

// ---------------- host ----------------
extern "C" void kernel_launch(void* const* d_in, const int* in_sizes, int n_in,
                              void* d_out, int out_size, void* d_ws, size_t ws_size,
                              hipStream_t stream) {
  const float* x = (const float*)d_in[0];
  const float* ln1g = (const float*)d_in[1];
  const float* ln1b = (const float*)d_in[2];
  const float* ln2g = (const float*)d_in[3];
  const float* ln2b = (const float*)d_in[4];
  const float* Wqkv = (const float*)d_in[5];
  const float* bqkv = (const float*)d_in[6];
  const float* Wproj = (const float*)d_in[7];
  const float* bproj = (const float*)d_in[8];
  const float* Wfc = (const float*)d_in[9];
  const float* bfc = (const float*)d_in[10];
  const float* Wout = (const float*)d_in[11];
  const float* bout = (const float*)d_in[12];

  char* ws = (char*)d_ws;
  const size_t MB = 1u << 20;
  // Liveness-based layout; peak 88 MB.
  u16* wt_out = (u16*)(ws + 0 * MB);    //  0- 8  [until out gemm]
  u16* hbuf = (u16*)(ws + 8 * MB);      //  8-16  [ln1->qkv; ln2->fc]
  float* x2 = (float*)(ws + 16 * MB);   // 16-32  [proj_reduce -> out_reduce]
  u16* ybuf = (u16*)(ws + 32 * MB);     // 32-40  [flash -> proj gemm]
  u16* qkvb = (u16*)(ws + 40 * MB);     // 40-64  [qkv gemm -> flash] (Q,K only)
  u16* vtb = (u16*)(ws + 64 * MB);      // 64-72  [qkv gemm (V^T) -> flash]
  u16* wt_qkv = (u16*)(ws + 72 * MB);   // 72-78  [until qkv gemm]
  u16* wt_proj = (u16*)(ws + 78 * MB);  // 78-80  [until proj gemm]
  u16* wt_fc = (u16*)(ws + 80 * MB);    // 80-88  [until fc gemm]
  u16* projP0 = (u16*)(ws + 40 * MB);   // 40-48  bf16 proj partials (qkvb dead)
  u16* projP1 = (u16*)(ws + 48 * MB);   // 48-56
  u16* m1 = (u16*)(ws + 40 * MB);       // 40-72  fc out bf16 (projP dead)
  u16* po0 = (u16*)(ws + 8 * MB);       // hbuf dead after fc
  u16* po1 = (u16*)(ws + 32 * MB);      // ybuf dead after proj
  u16* po2 = (u16*)(ws + 72 * MB);      // wt_qkv/wt_proj dead
  u16* po3 = (u16*)(ws + 80 * MB);      // wt_fc dead after fc

  // ln1 + all 4 weight transposes in one launch
  prep_kernel<<<4096 + 3072 + 1024 + 4096 + 4096, 256, 0, stream>>>(
      x, ln1g, ln1b, hbuf, Wqkv, wt_qkv, Wproj, wt_proj, Wfc, wt_fc, Wout, wt_out);

  // qkv GEMM; V-columns (n0>=2048) written transposed straight into vtb
  gemm_bt<F_BIAS | F_BF16 | F_VT><<<dim3(24, 32), 256, 0, stream>>>(
      hbuf, wt_qkv, bqkv, nullptr, qkvb, vtb, nullptr, nullptr, nullptr,
      4096, 3072, 1024, 1024);
  flash_attn<<<1024, 256, 0, stream>>>(qkvb, vtb, ybuf);

  // proj: split-K=2 into bf16 partials, then fused residual+bias+LN2
  gemm_bt<F_PART4><<<dim3(8, 32, 2), 256, 0, stream>>>(
      ybuf, wt_proj, nullptr, nullptr, nullptr, projP0, projP1, nullptr, nullptr,
      4096, 1024, 512, 1024);
  proj_reduce_ln<<<4096, 256, 0, stream>>>(x, bproj, projP0, projP1, ln2g, ln2b, x2, hbuf);

  gemm_bt<F_BIAS | F_RELU | F_BF16><<<dim3(32, 32), 256, 0, stream>>>(
      hbuf, wt_fc, bfc, nullptr, m1, nullptr, nullptr, nullptr, nullptr,
      4096, 4096, 1024, 1024);

  // out: split-K=4 into bf16 partials, then fused residual+bias reduce
  gemm_bt<F_PART4><<<dim3(8, 32, 4), 256, 0, stream>>>(
      m1, wt_out, nullptr, nullptr, nullptr, po0, po1, po2, po3,
      4096, 1024, 1024, 4096);
  out_reduce<<<4096, 256, 0, stream>>>(x2, bout, po0, po1, po2, po3, (float*)d_out);
}